// Round 4
// baseline (627.254 us; speedup 1.0000x reference)
//
#include <hip/hip_runtime.h>
#include <hip/hip_fp16.h>
#include <math.h>

// ESN: FFT(262144) over 32 cols -> fused(proj -> chunked tanh scan -> out matmul)
//      -> IFFT, REAL part only to d_out as float32 [T,32].
//
// Budget: d_out = 33.5 MB (float [T,32]); peak d_ws = 67 MB (one complex region).
// Forward FFT pass B runs in-place on ws (Xc left digit-swapped); outc stored
// fp16 in d_out; inverse writes real part only.

constexpr int TLEN = 262144;   // 2^18 = 512*512
constexpr int NCOL = 32;       // IN == OUT == 32 columns
constexpr int NR = 50;         // reservoir size
constexpr int SCH = 128;       // scan chunk length (2048 chunks)
constexpr int LW = 32;         // scan warmup rows
constexpr int LDSTR = 51;      // LDS row stride in float2 (odd -> fewer bank conflicts)
constexpr float TWO_PI = 6.28318530717958647692f;

__device__ __forceinline__ unsigned rev9(unsigned x) { return __brev(x) >> 23; }

// In-LDS 512-point radix-2 DIT FFT on 16 interleaved columns.
// lds[512][16], input must be bit-reversed (rev9) on load. 256 threads.
// Verified by hand at N=4 (both stages, complex twiddle) and via 4-step algebra.
template <int SIGN>
__device__ __forceinline__ void fft512(float2 (*lds)[16], int tid) {
  const int cl = tid & 15;
  const int bb = tid >> 4;
#pragma unroll
  for (int s = 1; s <= 9; ++s) {
    const int half = 1 << (s - 1);
    const float invm = 1.0f / (float)(1 << s);
#pragma unroll
    for (int i = 0; i < 16; ++i) {
      const int b = bb + (i << 4);            // butterfly slot 0..255
      const int j = b & (half - 1);
      const int g = b >> (s - 1);
      const int i1 = (g << s) + j;
      const int i2 = i1 + half;
      float2 a = lds[i1][cl];
      float2 c = lds[i2][cl];
      float ang = (float)SIGN * TWO_PI * ((float)j * invm);  // j/m exact
      float sw, cw;
      __sincosf(ang, &sw, &cw);
      float2 t = make_float2(c.x * cw - c.y * sw, c.x * sw + c.y * cw);
      lds[i1][cl] = make_float2(a.x + t.x, a.y + t.y);
      lds[i2][cl] = make_float2(a.x - t.x, a.y - t.y);
    }
    __syncthreads();
  }
}

// Pass A: input index n = nL + 512*nH; for block nL, FFT over nH -> kL,
// apply twiddle e^{SIGN*2pi*i*nL*kL/T}, store I[kL][nL] at ws row (kL*512+nL).
// INMODE 0: real float input (forward, X). INMODE 1: half2 complex input
// (inverse, outc in d_out), scaled by `scale` (1/T folded here).
template <int SIGN, int INMODE>
__global__ __launch_bounds__(256) void fft_passA(const void* __restrict__ vin,
                                                 float2* __restrict__ out,
                                                 float scale) {
  __shared__ float2 lds[512][16];
  const int nL = blockIdx.x;
  const int cg = blockIdx.y;
  const int tid = threadIdx.x;
  const int cl = tid & 15;
  const int cglob = cg * 16 + cl;
#pragma unroll
  for (int i = 0; i < 32; ++i) {
    const int nH = (tid >> 4) + i * 16;
    const size_t gidx = (size_t)(nL + (nH << 9)) * NCOL + cglob;
    float2 v;
    if (INMODE == 0) {
      v = make_float2(((const float*)vin)[gidx], 0.0f);
    } else {
      const float2 f = __half22float2(((const __half2*)vin)[gidx]);
      v = make_float2(f.x * scale, f.y * scale);
    }
    lds[rev9(nH)][cl] = v;
  }
  __syncthreads();
  fft512<SIGN>(lds, tid);
#pragma unroll
  for (int i = 0; i < 32; ++i) {
    const int kL = (tid >> 4) + i * 16;
    float2 v = lds[kL][cl];
    const float rev = (float)(nL * kL) * (1.0f / 262144.0f);  // exact (<2^24 / 2^18)
    const float ang = (float)SIGN * TWO_PI * rev;
    float sw, cw;
    __sincosf(ang, &sw, &cw);
    float2 w = make_float2(v.x * cw - v.y * sw, v.x * sw + v.y * cw);
    out[(size_t)(kL * 512 + nL) * NCOL + cglob] = w;
  }
}

// Pass B: for block kL, FFT over nL (rows kL*512+nL) -> kH.
// REALOUT=false (forward): store IN-PLACE at row (kL*512+kH)  -> result for
//   index k = kL + 512*kH lives at row (kL*512+kH) = digit-swapped layout.
//   Safe: each block reads all its 512 rows into LDS before any store.
// REALOUT=true (inverse): store real part only, natural order, float [T,32].
template <int SIGN, bool REALOUT>
__global__ __launch_bounds__(256) void fft_passB(float2* __restrict__ buf,
                                                 float* __restrict__ rout) {
  __shared__ float2 lds[512][16];
  const int kL = blockIdx.x;
  const int cg = blockIdx.y;
  const int tid = threadIdx.x;
  const int cl = tid & 15;
  const int cglob = cg * 16 + cl;
#pragma unroll
  for (int i = 0; i < 32; ++i) {
    const int nL = (tid >> 4) + i * 16;
    lds[rev9(nL)][cl] = buf[(size_t)(kL * 512 + nL) * NCOL + cglob];
  }
  __syncthreads();
  fft512<SIGN>(lds, tid);
#pragma unroll
  for (int i = 0; i < 32; ++i) {
    const int kH = (tid >> 4) + i * 16;
    if (REALOUT) {
      rout[(size_t)(kL + (kH << 9)) * NCOL + cglob] = lds[kH][cl].x;
    } else {
      buf[(size_t)(kL * 512 + kH) * NCOL + cglob] = lds[kH][cl];
    }
  }
}

// s' = ctanh(p + d*s);  ctanh(x+iy) = (sinh 2x + i sin 2y)/(cosh 2x + cos 2y)
__device__ __forceinline__ void esn_step(float d, float pr, float pi,
                                         float& sr, float& si) {
  const float x = fmaf(d, sr, pr);
  const float y = fmaf(d, si, pi);
  float x2 = 2.0f * x;
  x2 = fminf(fmaxf(x2, -30.0f), 30.0f);  // fp32-saturated beyond this
  const float E = __expf(x2);
  const float Ei = __expf(-x2);
  const float sh = 0.5f * (E - Ei);
  const float ch = 0.5f * (E + Ei);
  float s2, c2;
  __sincosf(2.0f * y, &s2, &c2);
  const float inv = __builtin_amdgcn_rcpf(ch + c2);
  sr = sh * inv;
  si = s2 * inv;
}

// Fused proj -> scan -> out matmul for one 128-step chunk.
// Xc is digit-swapped: row of frequency k at ((k&511)<<9)|(k>>9).
// Phase A (all 4 waves): proj rows [t0-W, t0+128) into LDS.
// Phase B (wave 0): serial s_t = ctanh(p_t + d*s_{t-1}) in LDS, in-place.
//   Warmup W=32 from zero state: |d|<=0.95 + tanh saturation (sigma(Re p)
//   ~1.2e3, P(unsaturated step) ~ 0.003 per lane) kill the init error.
// Phase C (all 4 waves): outc[t][o] = sum_r states[t][r]*Wout[o][r], fp16.
__global__ __launch_bounds__(256) void esn_scan_fused(
    const float2* __restrict__ Xc, const float* __restrict__ Win,
    const float* __restrict__ dvec, const float* __restrict__ Wout,
    __half2* __restrict__ outh) {
  __shared__ float2 lds[(SCH + LW) * LDSTR];  // 160*51*8 = 65,280 B
  const int chunk = blockIdx.x;
  const int t0 = chunk * SCH;
  const int W = (t0 > 0) ? LW : 0;
  const int rows = SCH + W;
  const int tid = threadIdx.x;

  // Phase A: proj
  if (tid < rows) {
    const int t = t0 - W + tid;
    const size_t row = (size_t)(((t & 511) << 9) | (t >> 9));  // digit-swap
    const float4* src = (const float4*)(Xc + row * NCOL);      // 256B aligned
    float2 xc[NCOL];
#pragma unroll
    for (int i = 0; i < NCOL / 2; ++i) {
      float4 v = src[i];
      xc[2 * i] = make_float2(v.x, v.y);
      xc[2 * i + 1] = make_float2(v.z, v.w);
    }
    for (int r = 0; r < NR; ++r) {
      float ar = 0.f, ai = 0.f;
#pragma unroll
      for (int c = 0; c < NCOL; ++c) {
        const float w = Win[r * NCOL + c];  // uniform -> scalar broadcast
        ar = fmaf(w, xc[c].x, ar);
        ai = fmaf(w, xc[c].y, ai);
      }
      lds[tid * LDSTR + r] = make_float2(ar, ai);
    }
  }
  __syncthreads();

  // Phase B: serial scan (wave 0; lockstep read-row-then-write-row is safe)
  if (tid < 64) {
    const int rl = tid < NR ? tid : NR - 1;
    const float d = dvec[rl];
    float sr = 0.f, si = 0.f;
    for (int i = 0; i < rows; ++i) {
      const float2 p = lds[i * LDSTR + rl];
      esn_step(d, p.x, p.y, sr, si);
      if (tid < NR) lds[i * LDSTR + tid] = make_float2(sr, si);
    }
  }
  __syncthreads();

  // Phase C: out matmul, fp16 complex store (natural k-order rows).
  for (int k = 0; k < 4; ++k) {
    const int idx = tid + k * 256;           // [0, 1024)
    const int tl = idx >> 3;                 // 0..127
    const int o0 = (idx & 7) * 4;            // 0,4,...,28
    const float2* srow = &lds[(W + tl) * LDSTR];
    float ar[4] = {0.f, 0.f, 0.f, 0.f};
    float ai[4] = {0.f, 0.f, 0.f, 0.f};
    for (int r = 0; r < NR; ++r) {
      const float2 s = srow[r];
#pragma unroll
      for (int j = 0; j < 4; ++j) {
        const float w = Wout[(o0 + j) * NR + r];
        ar[j] = fmaf(w, s.x, ar[j]);
        ai[j] = fmaf(w, s.y, ai[j]);
      }
    }
#pragma unroll
    for (int j = 0; j < 4; ++j)
      outh[(size_t)(t0 + tl) * NCOL + o0 + j] = __floats2half2_rn(ar[j], ai[j]);
  }
}

extern "C" void kernel_launch(void* const* d_in, const int* in_sizes, int n_in,
                              void* d_out, int out_size, void* d_ws, size_t ws_size,
                              hipStream_t stream) {
  const float* X = (const float*)d_in[0];      // [T,32] f32
  const float* Win = (const float*)d_in[1];    // [50,32] f32
  const float* dvec = (const float*)d_in[2];   // [50] f32
  const float* Wout = (const float*)d_in[3];   // [32,50] f32

  float2* Wa = (float2*)d_ws;                  // 67,108,864 B complex region
  dim3 fgrid(512, 2);

  // 1. fwd pass A: X (real) -> ws   (I[kL][nL] at row kL*512+nL)
  fft_passA<-1, 0><<<fgrid, 256, 0, stream>>>(X, Wa, 1.0f);
  // 2. fwd pass B: ws in-place      (Xc digit-swapped)
  fft_passB<-1, false><<<fgrid, 256, 0, stream>>>(Wa, nullptr);
  // 3. fused proj+scan+out: ws(Xc) -> d_out (outc, fp16 complex [T,32])
  esn_scan_fused<<<TLEN / SCH, 256, 0, stream>>>(Wa, Win, dvec, Wout,
                                                 (__half2*)d_out);
  // 4. inv pass A: d_out (fp16 outc) -> ws  (1/T folded into scale)
  fft_passA<1, 1><<<fgrid, 256, 0, stream>>>(d_out, Wa, 1.0f / 262144.0f);
  // 5. inv pass B: ws -> d_out, REAL part only, float32 [T,32]
  fft_passB<1, true><<<fgrid, 256, 0, stream>>>(Wa, (float*)d_out);

  (void)in_sizes; (void)n_in; (void)out_size; (void)ws_size;
}